// Round 13
// baseline (70.867 us; speedup 1.0000x reference)
//
#include <hip/hip_runtime.h>
#include <math.h>

// Tropical max/min-plus pseudo-matmul.
// out[b,u] = max_f(x[b,f] + w[f,u]) for u<128, min_f otherwise.
//
// R24 = R23 (packed adds, 67.66 best) + 2 INDEPENDENT blocks/CU at
// CONSTANT w-traffic (the clean phase-lock test R21 botched).
// R23 post-mortem: pk_add confirmed (-1.34us ~= predicted -1.7); VALU
// instruction floor reached (1.0 inst/cell: 4 pk_add + 4 max3 per 8 cells,
// no v_pk_max_f32 on CDNA). Residual over the 3.4us VALU floor must be
// stalls. Last untested theory: at 1 block/CU all waves share launch phase
// -> SMEM-wait/w-load stalls align -> SIMD idles. R21's 2-blocks/CU test
// was confounded: row-split doubled w L2 traffic (every block read all w).
// This round splits by UNITS: 512 blocks, block b = rows (b>>1)*8, unit
// half (b&1)*128. Per-block w read = 256KB -> total 128MB == R23. Per-wave
// work unchanged (8 rows x 128 units x 64 k). 8 waves/block, 2 blocks/CU,
// 4 waves/SIMD; co-resident blocks are launch-independent -> stalls
// decorrelate. LDS = real 32KB (no belt -- 2-block residency IS the goal);
// VGPR ~45 under waves_per_eu(4,4)'s 128 cap; SGPR ~75 of 102.
// Everything else byte-identical to R23: forced-SMEM x (s_load_dwordx2,
// SB(0)/lgkmcnt(0)/SB(0) fences, rule #18), v_pk_add_f32 op_sel broadcast,
// w VMEM f32x2 dist-1, block-uniform min/max (template on b&1).

#define FEAT  512
#define UNITS 256
#define BR    8            // rows per block
#define NW    8            // waves per block (8 k-slices, one unit-half)
#define KW    64           // k per wave
#define NS    (KW / 4)     // 16 steps, 4 k per step

typedef float f32x2 __attribute__((ext_vector_type(2)));

__device__ __forceinline__ float max3f(float a, float b, float c) {
    return fmaxf(fmaxf(a, b), c);   // v_max3_f32
}
__device__ __forceinline__ float min3f(float a, float b, float c) {
    return fminf(fminf(a, b), c);   // v_min3_f32
}

// one s_load_dwordx2 at compile-time byte offset (template -> guaranteed imm)
template<int OFF>
__device__ __forceinline__ void sload2(const float* __restrict__ p, f32x2& d) {
    asm volatile("s_load_dwordx2 %0, %1, %2" : "=s"(d) : "s"(p), "i"(OFF));
}

// 16 s_load_dwordx2: x[row0+r][k0..k0+3] as 2 SGPR pairs/row (offsets r*2048)
__device__ __forceinline__ void sload_xstep(const float* __restrict__ xp_s,
                                            f32x2* __restrict__ xb) {
#define SL(r) sload2<(r)*2048>(xp_s, xb[2*(r)]); sload2<(r)*2048+8>(xp_s, xb[2*(r)+1]);
    SL(0) SL(1) SL(2) SL(3) SL(4) SL(5) SL(6) SL(7)
#undef SL
}

__device__ __forceinline__ void smem_wait_fenced() {
    __builtin_amdgcn_sched_barrier(0);                 // pin cover-compute above
    asm volatile("s_waitcnt lgkmcnt(0)" ::: "memory"); // SMEM is OOO: only 0 valid
    __builtin_amdgcn_sched_barrier(0);                 // pin consumers below
}

// packed add, src0 = SGPR pair, lo half broadcast to both result lanes
__device__ __forceinline__ f32x2 pk_add_lo(f32x2 xs, f32x2 wv) {
    f32x2 d;
    asm("v_pk_add_f32 %0, %1, %2 op_sel:[0,0] op_sel_hi:[0,1]"
        : "=v"(d) : "s"(xs), "v"(wv));
    return d;
}
// packed add, hi half of the SGPR pair broadcast to both result lanes
__device__ __forceinline__ f32x2 pk_add_hi(f32x2 xs, f32x2 wv) {
    f32x2 d;
    asm("v_pk_add_f32 %0, %1, %2 op_sel:[1,0] op_sel_hi:[1,1]"
        : "=v"(d) : "s"(xs), "v"(wv));
    return d;
}

// 4 dwordx2: w[k0+j][u0..u0+1] -- 64 lanes x 8B = 512B contiguous
__device__ __forceinline__ void load_wstep(const float* __restrict__ wp, int s,
                                           f32x2* __restrict__ wb) {
    #pragma unroll
    for (int j = 0; j < 4; ++j)
        wb[j] = *(const f32x2*)(wp + (size_t)(s * 4 + j) * UNITS);
}

// per step: 8 rows x (4 pk_add + 4 max3/min3) = 64 VALU inst
template<bool ISMAX>
__device__ __forceinline__ void compute_step(const f32x2* __restrict__ xb,
                                             const f32x2* __restrict__ wq,
                                             f32x2* __restrict__ acc) {
    #pragma unroll
    for (int r = 0; r < BR; ++r) {
        const f32x2 t0 = pk_add_lo(xb[2 * r],     wq[0]);  // x[4s]   + w-row 4s
        const f32x2 t1 = pk_add_hi(xb[2 * r],     wq[1]);  // x[4s+1] + w-row 4s+1
        const f32x2 t2 = pk_add_lo(xb[2 * r + 1], wq[2]);  // x[4s+2] + w-row 4s+2
        const f32x2 t3 = pk_add_hi(xb[2 * r + 1], wq[3]);  // x[4s+3] + w-row 4s+3
        f32x2 A = acc[r];
        if (ISMAX) {
            A.x = max3f(A.x, t0.x, t1.x);  A.x = max3f(A.x, t2.x, t3.x);
            A.y = max3f(A.y, t0.y, t1.y);  A.y = max3f(A.y, t2.y, t3.y);
        } else {
            A.x = min3f(A.x, t0.x, t1.x);  A.x = min3f(A.x, t2.x, t3.x);
            A.y = min3f(A.y, t0.y, t1.y);  A.y = min3f(A.y, t2.y, t3.y);
        }
        acc[r] = A;
    }
}

// software pipeline: x (SMEM) and w (VMEM) one step ahead; one SMEM batch
// outstanding at each wait (R20/R23 structure, proven correct)
template<bool ISMAX>
__device__ __forceinline__ void main_loop(const float* __restrict__ xp,
                                          const float* __restrict__ wp,
                                          f32x2* __restrict__ acc) {
    f32x2 xA[BR * 2], xB[BR * 2];
    f32x2 wA[4], wB[4];
    sload_xstep(xp, xA);
    load_wstep(wp, 0, wA);
    smem_wait_fenced();                       // batch 0 ready
    #pragma unroll 1
    for (int s = 0; s < NS; s += 2) {
        sload_xstep(xp + (s + 1) * 4, xB);    // issue batch s+1
        load_wstep(wp, s + 1, wB);
        compute_step<ISMAX>(xA, wA, acc);     // covers batch s+1 latency
        smem_wait_fenced();                   // batch s+1 ready
        if (s + 2 < NS) {
            sload_xstep(xp + (s + 2) * 4, xA);
            load_wstep(wp, s + 2, wA);
        }
        compute_step<ISMAX>(xB, wB, acc);     // covers batch s+2 latency
        smem_wait_fenced();                   // batch s+2 ready (tail: no-op)
    }
}

__global__ __launch_bounds__(512)
__attribute__((amdgpu_waves_per_eu(4, 4)))
void tropical_kernel(const float* __restrict__ x,
                     const float* __restrict__ w,
                     float* __restrict__ out) {
    __shared__ float lds[NW * BR * 128];   // 32 KB real -> 2-block residency
    const int tid  = threadIdx.x;
    const int lane = tid & 63;
    const int wv   = __builtin_amdgcn_readfirstlane(tid >> 6);  // 0..7
    const int bid  = blockIdx.x;
    const int half = bid & 1;            // 0: max units 0-127, 1: min 128-255
    const int row0 = (bid >> 1) * BR;
    const int ks   = wv * KW;            // this wave's k origin (0..448)
    const int u0   = lane * 2;           // 2 units per lane, contiguous

    const float* xp = x + (size_t)row0 * FEAT + ks;              // uniform
    const float* wp = w + (size_t)ks * UNITS + half * 128 + u0;

    f32x2 acc[BR];
    const float init = half ? __builtin_inff() : -__builtin_inff();
    #pragma unroll
    for (int r = 0; r < BR; ++r)
        acc[r] = (f32x2){init, init};

    if (half == 0) main_loop<true >(xp, wp, acc);
    else           main_loop<false>(xp, wp, acc);

    // ---- partials to LDS: wave wv -> slot wv (8 slots x 8 rows x 128u) ----
    #pragma unroll
    for (int r = 0; r < BR; ++r)
        *(f32x2*)&lds[(wv * BR + r) * 128 + u0] = acc[r];   // 512B/wave-row
    __syncthreads();   // the kernel's only barrier

    // ---- combine 8 k-slice partials; thread -> float2 of output ----
    const int r  = tid >> 6;             // 0..7
    const int uo = (tid & 63) * 2;       // unit offset within the half
    f32x2 v = *(const f32x2*)&lds[(0 * BR + r) * 128 + uo];
    #pragma unroll
    for (int j = 1; j < NW; ++j) {
        const f32x2 p = *(const f32x2*)&lds[(j * BR + r) * 128 + uo];
        if (half == 0) { v.x = fmaxf(v.x, p.x); v.y = fmaxf(v.y, p.y); }
        else           { v.x = fminf(v.x, p.x); v.y = fminf(v.y, p.y); }
    }
    *(f32x2*)&out[(size_t)(row0 + r) * UNITS + half * 128 + uo] = v;
}

extern "C" void kernel_launch(void* const* d_in, const int* in_sizes, int n_in,
                              void* d_out, int out_size, void* d_ws, size_t ws_size,
                              hipStream_t stream) {
    const float* x = (const float*)d_in[0];   // (2048, 512)
    const float* w = (const float*)d_in[1];   // (512, 256)
    float* out = (float*)d_out;               // (2048, 256)

    // 512 blocks (256 row-groups x 2 unit-halves) = 2 independent blocks/CU,
    // 4 waves/SIMD; per-block w read 256KB -> total 128MB == R23.
    tropical_kernel<<<dim3(512), dim3(512), 0, stream>>>(x, w, out);
}

// Round 14
// 67.239 us; speedup vs baseline: 1.0539x; 1.0539x over previous
//
#include <hip/hip_runtime.h>
#include <math.h>

// Tropical max/min-plus pseudo-matmul.
// out[b,u] = max_f(x[b,f] + w[f,u]) for u<128, min_f otherwise.
//
// R25 = R23 (packed adds + SMEM x, best @67.66) + w at ISSUE-DISTANCE 2.
// R24 post-mortem: 2 independent blocks/CU at constant w-traffic HURT
// (70.9) -> phase-lock falsified cleanly; geometry reverted to R23.
// Remaining un-falsified theory: w-prefetch depth. R22's dist-2 test was
// CONFOUNDED: on the R19 base, x dbuf ate 64 VGPRs and the W quad pushed
// the 2x-unrolled body to the 128-cap edge. On R23's base x lives in
// SGPRs (VGPR ~45), so W0..W3 costs +16 -> ~62 of 128, huge slack.
// Arithmetic: dist-1 cover per w-batch = 1 compute_step = 64 inst ~128cyc
// < L2-hit 200-300cyc -> ~100-170cyc uncovered x 16 steps ~1us/wave,
// amplified by TA-queue correlation across same-CU waves = the residual.
// Change (ONLY this): steady-state x4-unrolled body, named W0..W3 (static
// indices, rule #20), w(s+2) issued before compute(s) -> 2-step cover
// ~256cyc >= L2 latency. Last iteration peeled (no conditionals in loop).
// x-SMEM fence cadence byte-identical to R23 (SB(0)/lgkmcnt(0)/SB(0),
// rule #18; SMEM OOO -> lgkmcnt(0) only; one x batch outstanding/wait).
// Pre-commit: null/hurt -> resubmit R23, declare achievable floor.

#define FEAT  512
#define UNITS 256
#define BR    8            // rows per block
#define NW    16           // waves per block (8 k-slices x 2 halves)
#define KW    64           // k per wave
#define NS    (KW / 4)     // 16 steps, 4 k per step
#define LDSZ  24576        // 96KB declared (occupancy belt); 64KB used

typedef float f32x2 __attribute__((ext_vector_type(2)));

__device__ __forceinline__ float max3f(float a, float b, float c) {
    return fmaxf(fmaxf(a, b), c);   // v_max3_f32
}
__device__ __forceinline__ float min3f(float a, float b, float c) {
    return fminf(fminf(a, b), c);   // v_min3_f32
}

// one s_load_dwordx2 at compile-time byte offset (template -> guaranteed imm)
template<int OFF>
__device__ __forceinline__ void sload2(const float* __restrict__ p, f32x2& d) {
    asm volatile("s_load_dwordx2 %0, %1, %2" : "=s"(d) : "s"(p), "i"(OFF));
}

// 16 s_load_dwordx2: x[row0+r][k0..k0+3] as 2 SGPR pairs/row (offsets r*2048)
__device__ __forceinline__ void sload_xstep(const float* __restrict__ xp_s,
                                            f32x2* __restrict__ xb) {
#define SL(r) sload2<(r)*2048>(xp_s, xb[2*(r)]); sload2<(r)*2048+8>(xp_s, xb[2*(r)+1]);
    SL(0) SL(1) SL(2) SL(3) SL(4) SL(5) SL(6) SL(7)
#undef SL
}

__device__ __forceinline__ void smem_wait_fenced() {
    __builtin_amdgcn_sched_barrier(0);                 // pin cover-compute above
    asm volatile("s_waitcnt lgkmcnt(0)" ::: "memory"); // SMEM is OOO: only 0 valid
    __builtin_amdgcn_sched_barrier(0);                 // pin consumers below
}

// packed add, src0 = SGPR pair, lo half broadcast to both result lanes
__device__ __forceinline__ f32x2 pk_add_lo(f32x2 xs, f32x2 wv) {
    f32x2 d;
    asm("v_pk_add_f32 %0, %1, %2 op_sel:[0,0] op_sel_hi:[0,1]"
        : "=v"(d) : "s"(xs), "v"(wv));
    return d;
}
// packed add, hi half of the SGPR pair broadcast to both result lanes
__device__ __forceinline__ f32x2 pk_add_hi(f32x2 xs, f32x2 wv) {
    f32x2 d;
    asm("v_pk_add_f32 %0, %1, %2 op_sel:[1,0] op_sel_hi:[1,1]"
        : "=v"(d) : "s"(xs), "v"(wv));
    return d;
}

// 4 dwordx2: w[k0+j][u0..u0+1] -- 64 lanes x 8B = 512B contiguous
__device__ __forceinline__ void load_wstep(const float* __restrict__ wp, int s,
                                           f32x2* __restrict__ wb) {
    #pragma unroll
    for (int j = 0; j < 4; ++j)
        wb[j] = *(const f32x2*)(wp + (size_t)(s * 4 + j) * UNITS);
}

// per step: 8 rows x (4 pk_add + 4 max3/min3) = 64 VALU inst
template<bool ISMAX>
__device__ __forceinline__ void compute_step(const f32x2* __restrict__ xb,
                                             const f32x2* __restrict__ wq,
                                             f32x2* __restrict__ acc) {
    #pragma unroll
    for (int r = 0; r < BR; ++r) {
        const f32x2 t0 = pk_add_lo(xb[2 * r],     wq[0]);  // x[4s]   + w-row 4s
        const f32x2 t1 = pk_add_hi(xb[2 * r],     wq[1]);  // x[4s+1] + w-row 4s+1
        const f32x2 t2 = pk_add_lo(xb[2 * r + 1], wq[2]);  // x[4s+2] + w-row 4s+2
        const f32x2 t3 = pk_add_hi(xb[2 * r + 1], wq[3]);  // x[4s+3] + w-row 4s+3
        f32x2 A = acc[r];
        if (ISMAX) {
            A.x = max3f(A.x, t0.x, t1.x);  A.x = max3f(A.x, t2.x, t3.x);
            A.y = max3f(A.y, t0.y, t1.y);  A.y = max3f(A.y, t2.y, t3.y);
        } else {
            A.x = min3f(A.x, t0.x, t1.x);  A.x = min3f(A.x, t2.x, t3.x);
            A.y = min3f(A.y, t0.y, t1.y);  A.y = min3f(A.y, t2.y, t3.y);
        }
        acc[r] = A;
    }
}

// pipeline: x (SMEM) one step ahead, fence cadence == R23; w TWO steps
// ahead via named quad-buffer, steady-state x4 body, last iter peeled.
template<bool ISMAX>
__device__ __forceinline__ void main_loop(const float* __restrict__ xp,
                                          const float* __restrict__ wp,
                                          f32x2* __restrict__ acc) {
    f32x2 xA[BR * 2], xB[BR * 2];
    f32x2 W0[4], W1[4], W2[4], W3[4];
    sload_xstep(xp, xA);
    load_wstep(wp, 0, W0);
    load_wstep(wp, 1, W1);                    // 2 w-batches in flight
    smem_wait_fenced();                       // x batch 0 ready
    #pragma unroll 1
    for (int s = 0; s < NS - 4; s += 4) {     // s = 0,4,8 (steps 0..11)
        sload_xstep(xp + (s + 1) * 4, xB);
        load_wstep(wp, s + 2, W2);            // dist-2
        compute_step<ISMAX>(xA, W0, acc);
        smem_wait_fenced();

        sload_xstep(xp + (s + 2) * 4, xA);
        load_wstep(wp, s + 3, W3);
        compute_step<ISMAX>(xB, W1, acc);
        smem_wait_fenced();

        sload_xstep(xp + (s + 3) * 4, xB);
        load_wstep(wp, s + 4, W0);
        compute_step<ISMAX>(xA, W2, acc);
        smem_wait_fenced();

        sload_xstep(xp + (s + 4) * 4, xA);
        load_wstep(wp, s + 5, W1);
        compute_step<ISMAX>(xB, W3, acc);
        smem_wait_fenced();
    }
    // peeled tail: steps 12..15; xA=x(12), W0=w(12), W1=w(13) already live
    sload_xstep(xp + 13 * 4, xB);
    load_wstep(wp, 14, W2);
    compute_step<ISMAX>(xA, W0, acc);
    smem_wait_fenced();

    sload_xstep(xp + 14 * 4, xA);
    load_wstep(wp, 15, W3);
    compute_step<ISMAX>(xB, W1, acc);
    smem_wait_fenced();

    sload_xstep(xp + 15 * 4, xB);
    compute_step<ISMAX>(xA, W2, acc);
    smem_wait_fenced();

    compute_step<ISMAX>(xB, W3, acc);
}

__global__ __launch_bounds__(1024)
__attribute__((amdgpu_waves_per_eu(4, 4)))
void tropical_kernel(const float* __restrict__ x,
                     const float* __restrict__ w,
                     float* __restrict__ out) {
    __shared__ float lds[LDSZ];   // 96KB declared (belt); 64KB used
    const int tid  = threadIdx.x;
    const int lane = tid & 63;
    const int wv   = __builtin_amdgcn_readfirstlane(tid >> 6);  // 0..15
    const int kslice = wv & 7;           // k origin index
    const int half   = wv >> 3;          // 0: max units 0-127, 1: min 128-255
    const int ks   = kslice * KW;
    const int u0   = lane * 2;           // 2 units per lane, contiguous
    const int row0 = blockIdx.x * BR;

    const float* xp = x + (size_t)row0 * FEAT + ks;          // uniform
    const float* wp = w + (size_t)ks * UNITS + half * 128 + u0;

    f32x2 acc[BR];
    const float init = half ? __builtin_inff() : -__builtin_inff();
    #pragma unroll
    for (int r = 0; r < BR; ++r)
        acc[r] = (f32x2){init, init};

    if (half == 0) main_loop<true >(xp, wp, acc);
    else           main_loop<false>(xp, wp, acc);

    // ---- partials to LDS: wave wv -> slot wv, 128 units of its half ----
    #pragma unroll
    for (int r = 0; r < BR; ++r)
        *(f32x2*)&lds[(wv * BR + r) * 128 + u0] = acc[r];   // 512B/wave-row
    __syncthreads();   // the kernel's only barrier

    // ---- combine 8 k-slice partials; thread -> float2 of output ----
    const int r  = tid >> 7;             // 0..7
    const int j2 = tid & 127;
    const int hh = j2 >> 6;              // wave-uniform: 0=max half, 1=min half
    const int uo = (j2 & 63) * 2;        // unit offset within the half
    f32x2 v = *(const f32x2*)&lds[((hh * 8 + 0) * BR + r) * 128 + uo];
    #pragma unroll
    for (int j = 1; j < 8; ++j) {
        const f32x2 p = *(const f32x2*)&lds[((hh * 8 + j) * BR + r) * 128 + uo];
        if (hh == 0) { v.x = fmaxf(v.x, p.x); v.y = fmaxf(v.y, p.y); }
        else         { v.x = fminf(v.x, p.x); v.y = fminf(v.y, p.y); }
    }
    *(f32x2*)&out[(size_t)(row0 + r) * UNITS + hh * 128 + uo] = v;
}

extern "C" void kernel_launch(void* const* d_in, const int* in_sizes, int n_in,
                              void* d_out, int out_size, void* d_ws, size_t ws_size,
                              hipStream_t stream) {
    const float* x = (const float*)d_in[0];   // (2048, 512)
    const float* w = (const float*)d_in[1];   // (512, 256)
    float* out = (float*)d_out;               // (2048, 256)

    // 256 blocks x 16 waves = 1 block/CU, 4 waves/SIMD (R23 geometry)
    tropical_kernel<<<dim3(2048 / BR), dim3(1024), 0, stream>>>(x, w, out);
}

// Round 15
// 66.879 us; speedup vs baseline: 1.0596x; 1.0054x over previous
//
#include <hip/hip_runtime.h>
#include <math.h>

// Tropical max/min-plus pseudo-matmul.
// out[b,u] = max_f(x[b,f] + w[f,u]) for u<128, min_f otherwise.
//
// R26 = R25 (best @67.24: packed adds + SMEM x + w dist-2) with x batches
// loaded as 8x s_load_dwordx4 instead of 16x s_load_dwordx2.
// R25 post-mortem: w dist-2 helped small (-0.42) -> w-latency was a minor
// term. Remaining residual model: the per-step SMEM fence tail. Each wave
// drains 16 scalar loads to lgkmcnt(0) per 128-cyc compute window; 16
// waves/CU burst 256 requests/step-round into the shared K$; x tile 16KB
// ~= K$ size -> partial miss to L2 (~250cyc > 128 cover) and the LAST
// return gates the fence. Halving request count (8 bigger loads) halves
// queue depth and tail-miss probability. Same 64 SGPRs (2 dbuf x 8 quads),
// same data, same fence cadence. f32x4 quad halves feed the existing
// f32x2 pk_add operands (sub-register copies; coalesce or cheap s_movs).
// Everything else byte-identical to R25: v_pk_add_f32 op_sel broadcast
// (lo: [0,0]/[0,1], hi: [1,0]/[1,1]), w VMEM f32x2 quad-buffer W0..W3 at
// issue-distance 2 (x4 body, peeled tail, static names, rule #20),
// SB(0)/lgkmcnt(0)/SB(0) fences (rule #18; SMEM OOO -> only 0 valid),
// wave-half min/max (no divergence, no sign math), 256 blocks x 16 waves,
// waves_per_eu(4,4), 96KB LDS belt (1 block/CU truth to the allocator).
// Pre-commit: null/hurt -> resubmit best, declare achievable floor.

#define FEAT  512
#define UNITS 256
#define BR    8            // rows per block
#define NW    16           // waves per block (8 k-slices x 2 halves)
#define KW    64           // k per wave
#define NS    (KW / 4)     // 16 steps, 4 k per step
#define LDSZ  24576        // 96KB declared (occupancy belt); 64KB used

typedef float f32x2 __attribute__((ext_vector_type(2)));
typedef float f32x4 __attribute__((ext_vector_type(4)));

__device__ __forceinline__ float max3f(float a, float b, float c) {
    return fmaxf(fmaxf(a, b), c);   // v_max3_f32
}
__device__ __forceinline__ float min3f(float a, float b, float c) {
    return fminf(fminf(a, b), c);   // v_min3_f32
}

// one s_load_dwordx4 at compile-time byte offset (template -> guaranteed imm)
template<int OFF>
__device__ __forceinline__ void sload4(const float* __restrict__ p, f32x4& d) {
    asm volatile("s_load_dwordx4 %0, %1, %2" : "=s"(d) : "s"(p), "i"(OFF));
}

// 8 s_load_dwordx4: x[row0+r][k0..k0+3] as one SGPR quad/row (offsets r*2048);
// halves split into the f32x2 pk_add operand layout (sub-register copies).
__device__ __forceinline__ void sload_xstep(const float* __restrict__ xp_s,
                                            f32x2* __restrict__ xb) {
    f32x4 q[BR];
    sload4<0 * 2048>(xp_s, q[0]);
    sload4<1 * 2048>(xp_s, q[1]);
    sload4<2 * 2048>(xp_s, q[2]);
    sload4<3 * 2048>(xp_s, q[3]);
    sload4<4 * 2048>(xp_s, q[4]);
    sload4<5 * 2048>(xp_s, q[5]);
    sload4<6 * 2048>(xp_s, q[6]);
    sload4<7 * 2048>(xp_s, q[7]);
    #pragma unroll
    for (int r = 0; r < BR; ++r) {
        xb[2 * r]     = (f32x2){q[r].x, q[r].y};
        xb[2 * r + 1] = (f32x2){q[r].z, q[r].w};
    }
}

__device__ __forceinline__ void smem_wait_fenced() {
    __builtin_amdgcn_sched_barrier(0);                 // pin cover-compute above
    asm volatile("s_waitcnt lgkmcnt(0)" ::: "memory"); // SMEM is OOO: only 0 valid
    __builtin_amdgcn_sched_barrier(0);                 // pin consumers below
}

// packed add, src0 = SGPR pair, lo half broadcast to both result lanes
__device__ __forceinline__ f32x2 pk_add_lo(f32x2 xs, f32x2 wv) {
    f32x2 d;
    asm("v_pk_add_f32 %0, %1, %2 op_sel:[0,0] op_sel_hi:[0,1]"
        : "=v"(d) : "s"(xs), "v"(wv));
    return d;
}
// packed add, hi half of the SGPR pair broadcast to both result lanes
__device__ __forceinline__ f32x2 pk_add_hi(f32x2 xs, f32x2 wv) {
    f32x2 d;
    asm("v_pk_add_f32 %0, %1, %2 op_sel:[1,0] op_sel_hi:[1,1]"
        : "=v"(d) : "s"(xs), "v"(wv));
    return d;
}

// 4 dwordx2: w[k0+j][u0..u0+1] -- 64 lanes x 8B = 512B contiguous
__device__ __forceinline__ void load_wstep(const float* __restrict__ wp, int s,
                                           f32x2* __restrict__ wb) {
    #pragma unroll
    for (int j = 0; j < 4; ++j)
        wb[j] = *(const f32x2*)(wp + (size_t)(s * 4 + j) * UNITS);
}

// per step: 8 rows x (4 pk_add + 4 max3/min3) = 64 VALU inst
template<bool ISMAX>
__device__ __forceinline__ void compute_step(const f32x2* __restrict__ xb,
                                             const f32x2* __restrict__ wq,
                                             f32x2* __restrict__ acc) {
    #pragma unroll
    for (int r = 0; r < BR; ++r) {
        const f32x2 t0 = pk_add_lo(xb[2 * r],     wq[0]);  // x[4s]   + w-row 4s
        const f32x2 t1 = pk_add_hi(xb[2 * r],     wq[1]);  // x[4s+1] + w-row 4s+1
        const f32x2 t2 = pk_add_lo(xb[2 * r + 1], wq[2]);  // x[4s+2] + w-row 4s+2
        const f32x2 t3 = pk_add_hi(xb[2 * r + 1], wq[3]);  // x[4s+3] + w-row 4s+3
        f32x2 A = acc[r];
        if (ISMAX) {
            A.x = max3f(A.x, t0.x, t1.x);  A.x = max3f(A.x, t2.x, t3.x);
            A.y = max3f(A.y, t0.y, t1.y);  A.y = max3f(A.y, t2.y, t3.y);
        } else {
            A.x = min3f(A.x, t0.x, t1.x);  A.x = min3f(A.x, t2.x, t3.x);
            A.y = min3f(A.y, t0.y, t1.y);  A.y = min3f(A.y, t2.y, t3.y);
        }
        acc[r] = A;
    }
}

// pipeline: x (SMEM) one step ahead, fence cadence == R23; w TWO steps
// ahead via named quad-buffer, steady-state x4 body, last iter peeled.
template<bool ISMAX>
__device__ __forceinline__ void main_loop(const float* __restrict__ xp,
                                          const float* __restrict__ wp,
                                          f32x2* __restrict__ acc) {
    f32x2 xA[BR * 2], xB[BR * 2];
    f32x2 W0[4], W1[4], W2[4], W3[4];
    sload_xstep(xp, xA);
    load_wstep(wp, 0, W0);
    load_wstep(wp, 1, W1);                    // 2 w-batches in flight
    smem_wait_fenced();                       // x batch 0 ready
    #pragma unroll 1
    for (int s = 0; s < NS - 4; s += 4) {     // s = 0,4,8 (steps 0..11)
        sload_xstep(xp + (s + 1) * 4, xB);
        load_wstep(wp, s + 2, W2);            // dist-2
        compute_step<ISMAX>(xA, W0, acc);
        smem_wait_fenced();

        sload_xstep(xp + (s + 2) * 4, xA);
        load_wstep(wp, s + 3, W3);
        compute_step<ISMAX>(xB, W1, acc);
        smem_wait_fenced();

        sload_xstep(xp + (s + 3) * 4, xB);
        load_wstep(wp, s + 4, W0);
        compute_step<ISMAX>(xA, W2, acc);
        smem_wait_fenced();

        sload_xstep(xp + (s + 4) * 4, xA);
        load_wstep(wp, s + 5, W1);
        compute_step<ISMAX>(xB, W3, acc);
        smem_wait_fenced();
    }
    // peeled tail: steps 12..15; xA=x(12), W0=w(12), W1=w(13) already live
    sload_xstep(xp + 13 * 4, xB);
    load_wstep(wp, 14, W2);
    compute_step<ISMAX>(xA, W0, acc);
    smem_wait_fenced();

    sload_xstep(xp + 14 * 4, xA);
    load_wstep(wp, 15, W3);
    compute_step<ISMAX>(xB, W1, acc);
    smem_wait_fenced();

    sload_xstep(xp + 15 * 4, xB);
    compute_step<ISMAX>(xA, W2, acc);
    smem_wait_fenced();

    compute_step<ISMAX>(xB, W3, acc);
}

__global__ __launch_bounds__(1024)
__attribute__((amdgpu_waves_per_eu(4, 4)))
void tropical_kernel(const float* __restrict__ x,
                     const float* __restrict__ w,
                     float* __restrict__ out) {
    __shared__ float lds[LDSZ];   // 96KB declared (belt); 64KB used
    const int tid  = threadIdx.x;
    const int lane = tid & 63;
    const int wv   = __builtin_amdgcn_readfirstlane(tid >> 6);  // 0..15
    const int kslice = wv & 7;           // k origin index
    const int half   = wv >> 3;          // 0: max units 0-127, 1: min 128-255
    const int ks   = kslice * KW;
    const int u0   = lane * 2;           // 2 units per lane, contiguous
    const int row0 = blockIdx.x * BR;

    const float* xp = x + (size_t)row0 * FEAT + ks;          // uniform
    const float* wp = w + (size_t)ks * UNITS + half * 128 + u0;

    f32x2 acc[BR];
    const float init = half ? __builtin_inff() : -__builtin_inff();
    #pragma unroll
    for (int r = 0; r < BR; ++r)
        acc[r] = (f32x2){init, init};

    if (half == 0) main_loop<true >(xp, wp, acc);
    else           main_loop<false>(xp, wp, acc);

    // ---- partials to LDS: wave wv -> slot wv, 128 units of its half ----
    #pragma unroll
    for (int r = 0; r < BR; ++r)
        *(f32x2*)&lds[(wv * BR + r) * 128 + u0] = acc[r];   // 512B/wave-row
    __syncthreads();   // the kernel's only barrier

    // ---- combine 8 k-slice partials; thread -> float2 of output ----
    const int r  = tid >> 7;             // 0..7
    const int j2 = tid & 127;
    const int hh = j2 >> 6;              // wave-uniform: 0=max half, 1=min half
    const int uo = (j2 & 63) * 2;        // unit offset within the half
    f32x2 v = *(const f32x2*)&lds[((hh * 8 + 0) * BR + r) * 128 + uo];
    #pragma unroll
    for (int j = 1; j < 8; ++j) {
        const f32x2 p = *(const f32x2*)&lds[((hh * 8 + j) * BR + r) * 128 + uo];
        if (hh == 0) { v.x = fmaxf(v.x, p.x); v.y = fmaxf(v.y, p.y); }
        else         { v.x = fminf(v.x, p.x); v.y = fminf(v.y, p.y); }
    }
    *(f32x2*)&out[(size_t)(row0 + r) * UNITS + hh * 128 + uo] = v;
}

extern "C" void kernel_launch(void* const* d_in, const int* in_sizes, int n_in,
                              void* d_out, int out_size, void* d_ws, size_t ws_size,
                              hipStream_t stream) {
    const float* x = (const float*)d_in[0];   // (2048, 512)
    const float* w = (const float*)d_in[1];   // (512, 256)
    float* out = (float*)d_out;               // (2048, 256)

    // 256 blocks x 16 waves = 1 block/CU, 4 waves/SIMD (R23/R25 geometry)
    tropical_kernel<<<dim3(2048 / BR), dim3(1024), 0, stream>>>(x, w, out);
}